// Round 10
// baseline (736.165 us; speedup 1.0000x reference)
//
#include <hip/hip_runtime.h>

// LSTM B=4096, T=2048, H=15.  R9 = R8 kernel + 2-waves/SIMD launch geometry.
// 16 lanes per batch element; lane u owns unit u, computes all 4 gates ->
// lane-local cell update, zero LDS, zero barriers.
// KEY CHANGE: grid 128 x block 512 (8 waves/block, 1 block/CU) -> 2 waves
// per SIMD on 128 CUs. Sibling wave's issue hides the ~153cy/step recurrence
// chain stall that 1-wave/SIMD (R4-R8) exposed. Idle half-machine is free:
// we are latency-bound, not throughput-bound.
// Chain cuts: x*W_ih folded into accumulator INIT (xt known early via
// prefetch); gate dot chains split 2x4 fdot2 + merge (chain 40->24cy).
// Gates: v_dot2_f32_f16 full-rate, f32 accumulate, weights pre-scaled by
// activation constants (i,f,o: -log2e; g: -2log2e), cs = 2L*c scaled state.

#define HID 15
#define T_LEN 2048
#define B_TOT 4096

typedef __fp16 v2h __attribute__((ext_vector_type(2)));

template<int CTRL>
__device__ __forceinline__ int dpp_i(int v) {
    return __builtin_amdgcn_update_dpp(0, v, CTRL, 0xF, 0xF, true);
}
template<int CTRL>
__device__ __forceinline__ float dpp_f(float v) {
    return __int_as_float(
        __builtin_amdgcn_update_dpp(0, __float_as_int(v), CTRL, 0xF, 0xF, true));
}
template<int CTRL>
__device__ __forceinline__ v2h dpp_h(v2h v) {
    int r = __builtin_amdgcn_update_dpp(0, __builtin_bit_cast(int, v),
                                        CTRL, 0xF, 0xF, true);
    return __builtin_bit_cast(v2h, r);
}

__global__ __launch_bounds__(512) __attribute__((amdgpu_waves_per_eu(2, 2)))
void lstm_seq_kernel(
    const float* __restrict__ x,      // (B, T)
    const float* __restrict__ W_ih,   // (60, 1)
    const float* __restrict__ W_hh,   // (60, 15)
    const float* __restrict__ b_ih,   // (60,)
    const float* __restrict__ b_hh,   // (60,)
    const float* __restrict__ W_lin,  // (1, 15)
    const float* __restrict__ b_lin,  // (1,)
    float* __restrict__ out)          // (B, T)
{
    const int tid = threadIdx.x;
    const int sub = tid & 15;                        // lane within 16-row
    const int u   = (sub < HID) ? sub : (HID - 1);   // lane 15 dups unit 14
    const int b   = blockIdx.x * 32 + (tid >> 4);    // batch element

    // ---- self-calibrate the PAIRED rotation map (mirrors runtime gather) --
    const int pr0 = sub;
    const int pr1 = dpp_i<0x121>(sub);               // ror:1
    int pos[16];
    pos[0]  = pr0;                pos[1]  = pr1;
    pos[2]  = dpp_i<0x122>(pr0);  pos[3]  = dpp_i<0x122>(pr1);
    pos[4]  = dpp_i<0x124>(pr0);  pos[5]  = dpp_i<0x124>(pr1);
    pos[6]  = dpp_i<0x126>(pr0);  pos[7]  = dpp_i<0x126>(pr1);
    pos[8]  = dpp_i<0x128>(pr0);  pos[9]  = dpp_i<0x128>(pr1);
    pos[10] = dpp_i<0x12A>(pr0);  pos[11] = dpp_i<0x12A>(pr1);
    pos[12] = dpp_i<0x12C>(pr0);  pos[13] = dpp_i<0x12C>(pr1);
    pos[14] = dpp_i<0x12E>(pr0);  pos[15] = dpp_i<0x12E>(pr1);

    // ---- f16 weights, pre-rotated + pre-scaled by activation constants ----
    const double Ld = 1.4426950408889634074;         // log2(e)
    const float  SI = (float)(-Ld);                  // rows i, f, o
    const float  SG = (float)(-2.0 * Ld);            // row g
    const int r0 = u, r1 = HID + u, r2 = 2 * HID + u, r3 = 3 * HID + u;
    v2h wi[8], wf[8], wg[8], wo[8];
#pragma unroll
    for (int j = 0; j < 8; ++j) {
        const int p0 = pos[2 * j], p1 = pos[2 * j + 1];
        const bool v0 = (p0 < HID), v1 = (p1 < HID);
        wi[j].x = (__fp16)(v0 ? W_hh[r0 * HID + p0] * SI : 0.0f);
        wi[j].y = (__fp16)(v1 ? W_hh[r0 * HID + p1] * SI : 0.0f);
        wf[j].x = (__fp16)(v0 ? W_hh[r1 * HID + p0] * SI : 0.0f);
        wf[j].y = (__fp16)(v1 ? W_hh[r1 * HID + p1] * SI : 0.0f);
        wg[j].x = (__fp16)(v0 ? W_hh[r2 * HID + p0] * SG : 0.0f);
        wg[j].y = (__fp16)(v1 ? W_hh[r2 * HID + p1] * SG : 0.0f);
        wo[j].x = (__fp16)(v0 ? W_hh[r3 * HID + p0] * SI : 0.0f);
        wo[j].y = (__fp16)(v1 ? W_hh[r3 * HID + p1] * SI : 0.0f);
    }
    const float wih_i = W_ih[r0] * SI, wih_f = W_ih[r1] * SI;
    const float wih_g = W_ih[r2] * SG, wih_o = W_ih[r3] * SI;
    const float bia_i = (b_ih[r0] + b_hh[r0]) * SI;
    const float bia_f = (b_ih[r1] + b_hh[r1]) * SI;
    const float bia_g = (b_ih[r2] + b_hh[r2]) * SG;
    const float bia_o = (b_ih[r3] + b_hh[r3]) * SI;
    const float wlin_m = (sub < HID) ? W_lin[sub] : 0.0f;   // lane15 masked
    const float blin = b_lin[0];
    const float C4L  = (float)(4.0 * Ld);            // for tg2 = 2L*tanh(g)
    const float CN2L = (float)(-2.0 * Ld);

    float cs = 0.0f;    // cs = 2*log2e * c   (scaled cell state)
    float hl = 0.0f;    // h for this lane's unit (f32)

    const float4* __restrict__ x4 = (const float4*)(x + (size_t)b * T_LEN);
    float4* __restrict__ o4       = (float4*)(out + (size_t)b * T_LEN);

    float4 xv = x4[0];
    for (int t0 = 0; t0 < T_LEN / 4; ++t0) {
        const int tn = (t0 + 1 < T_LEN / 4) ? (t0 + 1) : t0;
        const float4 xnext = x4[tn];                 // prefetch
        float ov[4];
#pragma unroll
        for (int s = 0; s < 4; ++s) {
            const float xt = (s == 0) ? xv.x : (s == 1) ? xv.y : (s == 2) ? xv.z : xv.w;

            // ---- packed h gather: 1 DPP + 1 cvt_pkrtz + 7 indep DPP ----
            const float h1 = dpp_f<0x121>(hl);       // ror:1 neighbor
            v2h pk[8];
            pk[0] = __builtin_amdgcn_cvt_pkrtz(hl, h1);
            pk[1] = dpp_h<0x122>(pk[0]);
            pk[2] = dpp_h<0x124>(pk[0]);
            pk[3] = dpp_h<0x126>(pk[0]);
            pk[4] = dpp_h<0x128>(pk[0]);
            pk[5] = dpp_h<0x12A>(pk[0]);
            pk[6] = dpp_h<0x12C>(pk[0]);
            pk[7] = dpp_h<0x12E>(pk[0]);

            // ---- 4 gate rows: x/bias folded into init (off the dot chain),
            //      each row = 2 independent 4-deep fdot2 chains + merge ----
            float ai0 = fmaf(xt, wih_i, bia_i), ai1 = 0.0f;
            float af0 = fmaf(xt, wih_f, bia_f), af1 = 0.0f;
            float ag0 = fmaf(xt, wih_g, bia_g), ag1 = 0.0f;
            float ao0 = fmaf(xt, wih_o, bia_o), ao1 = 0.0f;
#pragma unroll
            for (int j = 0; j < 4; ++j) {
                ai0 = __builtin_amdgcn_fdot2(pk[j],     wi[j],     ai0, false);
                ai1 = __builtin_amdgcn_fdot2(pk[j + 4], wi[j + 4], ai1, false);
                af0 = __builtin_amdgcn_fdot2(pk[j],     wf[j],     af0, false);
                af1 = __builtin_amdgcn_fdot2(pk[j + 4], wf[j + 4], af1, false);
                ag0 = __builtin_amdgcn_fdot2(pk[j],     wg[j],     ag0, false);
                ag1 = __builtin_amdgcn_fdot2(pk[j + 4], wg[j + 4], ag1, false);
                ao0 = __builtin_amdgcn_fdot2(pk[j],     wo[j],     ao0, false);
                ao1 = __builtin_amdgcn_fdot2(pk[j + 4], wo[j + 4], ao1, false);
            }
            const float gi = ai0 + ai1;              // = -L  * raw_i
            const float gf = af0 + af1;              // = -L  * raw_f
            const float gg = ag0 + ag1;              // = -2L * raw_g
            const float go = ao0 + ao1;              // = -L  * raw_o

            // ---- activations: args pre-scaled, exp2 direct ----
            const float si = __builtin_amdgcn_rcpf(1.0f + __builtin_amdgcn_exp2f(gi));
            const float sf = __builtin_amdgcn_rcpf(1.0f + __builtin_amdgcn_exp2f(gf));
            const float rg = __builtin_amdgcn_rcpf(1.0f + __builtin_amdgcn_exp2f(gg));
            const float so = __builtin_amdgcn_rcpf(1.0f + __builtin_amdgcn_exp2f(go));
            const float tg2 = fmaf(C4L, rg, CN2L);   // = 2L * tanh(raw_g)

            // ---- scaled cell update: cs = sf*cs + si*tg2  (= 2L*c_new) ----
            cs = fmaf(sf, cs, si * tg2);
            const float rc = __builtin_amdgcn_rcpf(1.0f + __builtin_amdgcn_exp2f(-cs));
            const float tso = so + so;               // off-chain
            hl = fmaf(tso, rc, -so);                 // = so * tanh(c_new)

            // ---- out-projection: DPP butterfly (involutions, off-chain) ----
            float p = hl * wlin_m;
            p += dpp_f<0x0B1>(p);   // quad_perm xor1
            p += dpp_f<0x04E>(p);   // quad_perm xor2
            p += dpp_f<0x140>(p);   // row_mirror
            p += dpp_f<0x141>(p);   // half_mirror
            ov[s] = p + blin;
        }
        if (sub == 0) {
            o4[t0] = make_float4(ov[0], ov[1], ov[2], ov[3]);
        }
        xv = xnext;
    }
}

extern "C" void kernel_launch(void* const* d_in, const int* in_sizes, int n_in,
                              void* d_out, int out_size, void* d_ws, size_t ws_size,
                              hipStream_t stream) {
    const float* x     = (const float*)d_in[0];
    const float* W_ih  = (const float*)d_in[1];
    const float* W_hh  = (const float*)d_in[2];
    const float* b_ih  = (const float*)d_in[3];
    const float* b_hh  = (const float*)d_in[4];
    const float* W_lin = (const float*)d_in[5];
    const float* b_lin = (const float*)d_in[6];
    float* out = (float*)d_out;

    dim3 grid(B_TOT / 32);   // 128 blocks of 32 elements
    dim3 block(512);         // 8 waves/block = 2 waves/SIMD on 128 CUs
    lstm_seq_kernel<<<grid, block, 0, stream>>>(x, W_ih, W_hh, b_ih, b_hh,
                                                W_lin, b_lin, out);
}

// Round 11
// 430.205 us; speedup vs baseline: 1.7112x; 1.7112x over previous
//
#include <hip/hip_runtime.h>

// LSTM B=4096, T=2048, H=15.  R10 = R8 frame (256x256 launch, waves_per_eu(1,1))
// + R9's two chain cuts (which were good; R9's regression was its 128-CU
// geometry: per-SIMD issue doubled, 750 > 528).
// 16 lanes per batch element; lane u owns unit u, computes all 4 gates ->
// lane-local cell update, zero LDS, zero barriers. 1024 waves = 1/SIMD.
// Gates: v_dot2_f32_f16, f32 accumulate, weights pre-scaled by activation
// constants (i,f,o: -log2e; g: -2log2e); cs = 2L*c scaled cell state.
// Chain cuts: x*W_ih+bias folded into accumulator INIT (xt known one iter
// early via prefetch); each gate = 2 independent 4-deep fdot2 chains + merge.
// Conservation law (R5/R9): per-wave issue ~375cy is fixed by 1-unit-per-lane;
// wave count pinned at 1024 -> only chain length and inst count are levers.

#define HID 15
#define T_LEN 2048
#define B_TOT 4096

typedef __fp16 v2h __attribute__((ext_vector_type(2)));

template<int CTRL>
__device__ __forceinline__ int dpp_i(int v) {
    return __builtin_amdgcn_update_dpp(0, v, CTRL, 0xF, 0xF, true);
}
template<int CTRL>
__device__ __forceinline__ float dpp_f(float v) {
    return __int_as_float(
        __builtin_amdgcn_update_dpp(0, __float_as_int(v), CTRL, 0xF, 0xF, true));
}
template<int CTRL>
__device__ __forceinline__ v2h dpp_h(v2h v) {
    int r = __builtin_amdgcn_update_dpp(0, __builtin_bit_cast(int, v),
                                        CTRL, 0xF, 0xF, true);
    return __builtin_bit_cast(v2h, r);
}

__global__ __launch_bounds__(256) __attribute__((amdgpu_waves_per_eu(1, 1)))
void lstm_seq_kernel(
    const float* __restrict__ x,      // (B, T)
    const float* __restrict__ W_ih,   // (60, 1)
    const float* __restrict__ W_hh,   // (60, 15)
    const float* __restrict__ b_ih,   // (60,)
    const float* __restrict__ b_hh,   // (60,)
    const float* __restrict__ W_lin,  // (1, 15)
    const float* __restrict__ b_lin,  // (1,)
    float* __restrict__ out)          // (B, T)
{
    const int tid = threadIdx.x;
    const int sub = tid & 15;                        // lane within 16-row
    const int u   = (sub < HID) ? sub : (HID - 1);   // lane 15 dups unit 14
    const int b   = blockIdx.x * 16 + (tid >> 4);    // batch element

    // ---- self-calibrate the PAIRED rotation map (mirrors runtime gather) --
    const int pr0 = sub;
    const int pr1 = dpp_i<0x121>(sub);               // ror:1
    int pos[16];
    pos[0]  = pr0;                pos[1]  = pr1;
    pos[2]  = dpp_i<0x122>(pr0);  pos[3]  = dpp_i<0x122>(pr1);
    pos[4]  = dpp_i<0x124>(pr0);  pos[5]  = dpp_i<0x124>(pr1);
    pos[6]  = dpp_i<0x126>(pr0);  pos[7]  = dpp_i<0x126>(pr1);
    pos[8]  = dpp_i<0x128>(pr0);  pos[9]  = dpp_i<0x128>(pr1);
    pos[10] = dpp_i<0x12A>(pr0);  pos[11] = dpp_i<0x12A>(pr1);
    pos[12] = dpp_i<0x12C>(pr0);  pos[13] = dpp_i<0x12C>(pr1);
    pos[14] = dpp_i<0x12E>(pr0);  pos[15] = dpp_i<0x12E>(pr1);

    // ---- f16 weights, pre-rotated + pre-scaled by activation constants ----
    const double Ld = 1.4426950408889634074;         // log2(e)
    const float  SI = (float)(-Ld);                  // rows i, f, o
    const float  SG = (float)(-2.0 * Ld);            // row g
    const int r0 = u, r1 = HID + u, r2 = 2 * HID + u, r3 = 3 * HID + u;
    v2h wi[8], wf[8], wg[8], wo[8];
#pragma unroll
    for (int j = 0; j < 8; ++j) {
        const int p0 = pos[2 * j], p1 = pos[2 * j + 1];
        const bool v0 = (p0 < HID), v1 = (p1 < HID);
        wi[j].x = (__fp16)(v0 ? W_hh[r0 * HID + p0] * SI : 0.0f);
        wi[j].y = (__fp16)(v1 ? W_hh[r0 * HID + p1] * SI : 0.0f);
        wf[j].x = (__fp16)(v0 ? W_hh[r1 * HID + p0] * SI : 0.0f);
        wf[j].y = (__fp16)(v1 ? W_hh[r1 * HID + p1] * SI : 0.0f);
        wg[j].x = (__fp16)(v0 ? W_hh[r2 * HID + p0] * SG : 0.0f);
        wg[j].y = (__fp16)(v1 ? W_hh[r2 * HID + p1] * SG : 0.0f);
        wo[j].x = (__fp16)(v0 ? W_hh[r3 * HID + p0] * SI : 0.0f);
        wo[j].y = (__fp16)(v1 ? W_hh[r3 * HID + p1] * SI : 0.0f);
    }
    const float wih_i = W_ih[r0] * SI, wih_f = W_ih[r1] * SI;
    const float wih_g = W_ih[r2] * SG, wih_o = W_ih[r3] * SI;
    const float bia_i = (b_ih[r0] + b_hh[r0]) * SI;
    const float bia_f = (b_ih[r1] + b_hh[r1]) * SI;
    const float bia_g = (b_ih[r2] + b_hh[r2]) * SG;
    const float bia_o = (b_ih[r3] + b_hh[r3]) * SI;
    const float wlin_m = (sub < HID) ? W_lin[sub] : 0.0f;   // lane15 masked
    const float blin = b_lin[0];
    const float C4L  = (float)(4.0 * Ld);            // for tg2 = 2L*tanh(g)
    const float CN2L = (float)(-2.0 * Ld);

    float cs = 0.0f;    // cs = 2*log2e * c   (scaled cell state)
    float hl = 0.0f;    // h for this lane's unit (f32)

    const float4* __restrict__ x4 = (const float4*)(x + (size_t)b * T_LEN);
    float4* __restrict__ o4       = (float4*)(out + (size_t)b * T_LEN);

    float4 xv = x4[0];
    for (int t0 = 0; t0 < T_LEN / 4; ++t0) {
        const int tn = (t0 + 1 < T_LEN / 4) ? (t0 + 1) : t0;
        const float4 xnext = x4[tn];                 // prefetch
        float ov[4];
#pragma unroll
        for (int s = 0; s < 4; ++s) {
            const float xt = (s == 0) ? xv.x : (s == 1) ? xv.y : (s == 2) ? xv.z : xv.w;

            // ---- packed h gather: 1 DPP + 1 cvt_pkrtz + 7 indep DPP ----
            const float h1 = dpp_f<0x121>(hl);       // ror:1 neighbor
            v2h pk[8];
            pk[0] = __builtin_amdgcn_cvt_pkrtz(hl, h1);
            pk[1] = dpp_h<0x122>(pk[0]);
            pk[2] = dpp_h<0x124>(pk[0]);
            pk[3] = dpp_h<0x126>(pk[0]);
            pk[4] = dpp_h<0x128>(pk[0]);
            pk[5] = dpp_h<0x12A>(pk[0]);
            pk[6] = dpp_h<0x12C>(pk[0]);
            pk[7] = dpp_h<0x12E>(pk[0]);

            // ---- 4 gate rows: x/bias folded into init (off the dot chain),
            //      each row = 2 independent 4-deep fdot2 chains + merge ----
            float ai0 = fmaf(xt, wih_i, bia_i), ai1 = 0.0f;
            float af0 = fmaf(xt, wih_f, bia_f), af1 = 0.0f;
            float ag0 = fmaf(xt, wih_g, bia_g), ag1 = 0.0f;
            float ao0 = fmaf(xt, wih_o, bia_o), ao1 = 0.0f;
#pragma unroll
            for (int j = 0; j < 4; ++j) {
                ai0 = __builtin_amdgcn_fdot2(pk[j],     wi[j],     ai0, false);
                ai1 = __builtin_amdgcn_fdot2(pk[j + 4], wi[j + 4], ai1, false);
                af0 = __builtin_amdgcn_fdot2(pk[j],     wf[j],     af0, false);
                af1 = __builtin_amdgcn_fdot2(pk[j + 4], wf[j + 4], af1, false);
                ag0 = __builtin_amdgcn_fdot2(pk[j],     wg[j],     ag0, false);
                ag1 = __builtin_amdgcn_fdot2(pk[j + 4], wg[j + 4], ag1, false);
                ao0 = __builtin_amdgcn_fdot2(pk[j],     wo[j],     ao0, false);
                ao1 = __builtin_amdgcn_fdot2(pk[j + 4], wo[j + 4], ao1, false);
            }
            const float gi = ai0 + ai1;              // = -L  * raw_i
            const float gf = af0 + af1;              // = -L  * raw_f
            const float gg = ag0 + ag1;              // = -2L * raw_g
            const float go = ao0 + ao1;              // = -L  * raw_o

            // ---- activations: args pre-scaled, exp2 direct ----
            const float si = __builtin_amdgcn_rcpf(1.0f + __builtin_amdgcn_exp2f(gi));
            const float sf = __builtin_amdgcn_rcpf(1.0f + __builtin_amdgcn_exp2f(gf));
            const float rg = __builtin_amdgcn_rcpf(1.0f + __builtin_amdgcn_exp2f(gg));
            const float so = __builtin_amdgcn_rcpf(1.0f + __builtin_amdgcn_exp2f(go));
            const float tg2 = fmaf(C4L, rg, CN2L);   // = 2L * tanh(raw_g)

            // ---- scaled cell update: cs = sf*cs + si*tg2  (= 2L*c_new) ----
            cs = fmaf(sf, cs, si * tg2);
            const float rc = __builtin_amdgcn_rcpf(1.0f + __builtin_amdgcn_exp2f(-cs));
            const float tso = so + so;               // off-chain
            hl = fmaf(tso, rc, -so);                 // = so * tanh(c_new)

            // ---- out-projection: DPP butterfly (involutions, off-chain) ----
            float p = hl * wlin_m;
            p += dpp_f<0x0B1>(p);   // quad_perm xor1
            p += dpp_f<0x04E>(p);   // quad_perm xor2
            p += dpp_f<0x140>(p);   // row_mirror
            p += dpp_f<0x141>(p);   // half_mirror
            ov[s] = p + blin;
        }
        if (sub == 0) {
            o4[t0] = make_float4(ov[0], ov[1], ov[2], ov[3]);
        }
        xv = xnext;
    }
}

extern "C" void kernel_launch(void* const* d_in, const int* in_sizes, int n_in,
                              void* d_out, int out_size, void* d_ws, size_t ws_size,
                              hipStream_t stream) {
    const float* x     = (const float*)d_in[0];
    const float* W_ih  = (const float*)d_in[1];
    const float* W_hh  = (const float*)d_in[2];
    const float* b_ih  = (const float*)d_in[3];
    const float* b_hh  = (const float*)d_in[4];
    const float* W_lin = (const float*)d_in[5];
    const float* b_lin = (const float*)d_in[6];
    float* out = (float*)d_out;

    dim3 grid(B_TOT / 16);   // 256 blocks of 16 elements
    dim3 block(256);         // 4 waves/block, 4 elements/wave -> 1024 waves
    lstm_seq_kernel<<<grid, block, 0, stream>>>(x, W_ih, W_hh, b_ih, b_hh,
                                                W_lin, b_lin, out);
}

// Round 12
// 392.924 us; speedup vs baseline: 1.8736x; 1.0949x over previous
//
#include <hip/hip_runtime.h>

// LSTM B=4096, T=2048, H=15.  R11 = R8 exact structure (best: 451us rocprof)
// with ONE change: output projection = 8 lane-local fdot2 on the carried
// rotated-h pack (each lane holds ALL 16 h's in pk[0..7]) against a
// pre-rotated dup-masked f16 W_lin -> removes the 4-hop serial DPP butterfly
// (last dependent-DPP chain + its RAW hazards). pk is loop-carried; gather
// moved after the cell update (identical dataflow/chain length).
// R10 lesson: issue-bound; dot-chain splits cost issue for nothing.
// Geometry law: 1 lane = 1 (element,unit) -> 1024 waves = exactly 1/SIMD;
// all other geometries (R5/R9) lose. MFMA rejected: 1 wave/CU occupancy.

#define HID 15
#define T_LEN 2048
#define B_TOT 4096

typedef __fp16 v2h __attribute__((ext_vector_type(2)));

template<int CTRL>
__device__ __forceinline__ int dpp_i(int v) {
    return __builtin_amdgcn_update_dpp(0, v, CTRL, 0xF, 0xF, true);
}
template<int CTRL>
__device__ __forceinline__ float dpp_f(float v) {
    return __int_as_float(
        __builtin_amdgcn_update_dpp(0, __float_as_int(v), CTRL, 0xF, 0xF, true));
}
template<int CTRL>
__device__ __forceinline__ v2h dpp_h(v2h v) {
    int r = __builtin_amdgcn_update_dpp(0, __builtin_bit_cast(int, v),
                                        CTRL, 0xF, 0xF, true);
    return __builtin_bit_cast(v2h, r);
}

__global__ __launch_bounds__(256) __attribute__((amdgpu_waves_per_eu(1, 1)))
void lstm_seq_kernel(
    const float* __restrict__ x,      // (B, T)
    const float* __restrict__ W_ih,   // (60, 1)
    const float* __restrict__ W_hh,   // (60, 15)
    const float* __restrict__ b_ih,   // (60,)
    const float* __restrict__ b_hh,   // (60,)
    const float* __restrict__ W_lin,  // (1, 15)
    const float* __restrict__ b_lin,  // (1,)
    float* __restrict__ out)          // (B, T)
{
    const int tid = threadIdx.x;
    const int sub = tid & 15;                        // lane within 16-row
    const int u   = (sub < HID) ? sub : (HID - 1);   // lane 15 dups unit 14
    const int b   = blockIdx.x * 16 + (tid >> 4);    // batch element

    // ---- self-calibrate the PAIRED rotation map (mirrors runtime gather) --
    const int pr0 = sub;
    const int pr1 = dpp_i<0x121>(sub);               // ror:1
    int pos[16];
    pos[0]  = pr0;                pos[1]  = pr1;
    pos[2]  = dpp_i<0x122>(pr0);  pos[3]  = dpp_i<0x122>(pr1);
    pos[4]  = dpp_i<0x124>(pr0);  pos[5]  = dpp_i<0x124>(pr1);
    pos[6]  = dpp_i<0x126>(pr0);  pos[7]  = dpp_i<0x126>(pr1);
    pos[8]  = dpp_i<0x128>(pr0);  pos[9]  = dpp_i<0x128>(pr1);
    pos[10] = dpp_i<0x12A>(pr0);  pos[11] = dpp_i<0x12A>(pr1);
    pos[12] = dpp_i<0x12C>(pr0);  pos[13] = dpp_i<0x12C>(pr1);
    pos[14] = dpp_i<0x12E>(pr0);  pos[15] = dpp_i<0x12E>(pr1);

    // ---- f16 weights, pre-rotated + pre-scaled by activation constants ----
    const double Ld = 1.4426950408889634074;         // log2(e)
    const float  SI = (float)(-Ld);                  // rows i, f, o
    const float  SG = (float)(-2.0 * Ld);            // row g
    const int r0 = u, r1 = HID + u, r2 = 2 * HID + u, r3 = 3 * HID + u;
    v2h wi[8], wf[8], wg[8], wo[8], wlr[8];
#pragma unroll
    for (int j = 0; j < 8; ++j) {
        const int p0 = pos[2 * j], p1 = pos[2 * j + 1];
        const bool v0 = (p0 < HID), v1 = (p1 < HID);
        wi[j].x = (__fp16)(v0 ? W_hh[r0 * HID + p0] * SI : 0.0f);
        wi[j].y = (__fp16)(v1 ? W_hh[r0 * HID + p1] * SI : 0.0f);
        wf[j].x = (__fp16)(v0 ? W_hh[r1 * HID + p0] * SI : 0.0f);
        wf[j].y = (__fp16)(v1 ? W_hh[r1 * HID + p1] * SI : 0.0f);
        wg[j].x = (__fp16)(v0 ? W_hh[r2 * HID + p0] * SG : 0.0f);
        wg[j].y = (__fp16)(v1 ? W_hh[r2 * HID + p1] * SG : 0.0f);
        wo[j].x = (__fp16)(v0 ? W_hh[r3 * HID + p0] * SI : 0.0f);
        wo[j].y = (__fp16)(v1 ? W_hh[r3 * HID + p1] * SI : 0.0f);
        // projection weights: same rotation, dup slot masked
        wlr[j].x = (__fp16)(v0 ? W_lin[p0] : 0.0f);
        wlr[j].y = (__fp16)(v1 ? W_lin[p1] : 0.0f);
    }
    const float wih_i = W_ih[r0] * SI, wih_f = W_ih[r1] * SI;
    const float wih_g = W_ih[r2] * SG, wih_o = W_ih[r3] * SI;
    const float bia_i = (b_ih[r0] + b_hh[r0]) * SI;
    const float bia_f = (b_ih[r1] + b_hh[r1]) * SI;
    const float bia_g = (b_ih[r2] + b_hh[r2]) * SG;
    const float bia_o = (b_ih[r3] + b_hh[r3]) * SI;
    const float blin = b_lin[0];
    const float C4L  = (float)(4.0 * Ld);            // for tg2 = 2L*tanh(g)
    const float CN2L = (float)(-2.0 * Ld);

    float cs = 0.0f;    // cs = 2*log2e * c   (scaled cell state)
    // loop-carried rotated h pack (h == 0 initially)
    v2h pk[8];
#pragma unroll
    for (int j = 0; j < 8; ++j) pk[j] = (v2h)(__fp16)0.0f;

    const float4* __restrict__ x4 = (const float4*)(x + (size_t)b * T_LEN);
    float4* __restrict__ o4       = (float4*)(out + (size_t)b * T_LEN);

    float4 xv = x4[0];
    for (int t0 = 0; t0 < T_LEN / 4; ++t0) {
        const int tn = (t0 + 1 < T_LEN / 4) ? (t0 + 1) : t0;
        const float4 xnext = x4[tn];                 // prefetch
        float ov[4];
#pragma unroll
        for (int s = 0; s < 4; ++s) {
            const float xt = (s == 0) ? xv.x : (s == 1) ? xv.y : (s == 2) ? xv.z : xv.w;

            // ---- 4 gate rows via full-rate f16 dot2, f32 accumulate ----
            float ai = bia_i, af = bia_f, ag = bia_g, aq = bia_o;
#pragma unroll
            for (int j = 0; j < 8; ++j) {
                ai = __builtin_amdgcn_fdot2(pk[j], wi[j], ai, false);
                af = __builtin_amdgcn_fdot2(pk[j], wf[j], af, false);
                ag = __builtin_amdgcn_fdot2(pk[j], wg[j], ag, false);
                aq = __builtin_amdgcn_fdot2(pk[j], wo[j], aq, false);
            }
            const float gi = fmaf(xt, wih_i, ai);    // = -L  * raw_i
            const float gf = fmaf(xt, wih_f, af);    // = -L  * raw_f
            const float gg = fmaf(xt, wih_g, ag);    // = -2L * raw_g
            const float go = fmaf(xt, wih_o, aq);    // = -L  * raw_o

            // ---- activations: args pre-scaled, exp2 direct ----
            const float si = __builtin_amdgcn_rcpf(1.0f + __builtin_amdgcn_exp2f(gi));
            const float sf = __builtin_amdgcn_rcpf(1.0f + __builtin_amdgcn_exp2f(gf));
            const float rg = __builtin_amdgcn_rcpf(1.0f + __builtin_amdgcn_exp2f(gg));
            const float so = __builtin_amdgcn_rcpf(1.0f + __builtin_amdgcn_exp2f(go));
            const float tg2 = fmaf(C4L, rg, CN2L);   // = 2L * tanh(raw_g)

            // ---- scaled cell update: cs = sf*cs + si*tg2  (= 2L*c_new) ----
            cs = fmaf(sf, cs, si * tg2);
            const float rc = __builtin_amdgcn_rcpf(1.0f + __builtin_amdgcn_exp2f(-cs));
            const float tso = so + so;               // off-chain
            const float hl = fmaf(tso, rc, -so);     // = so * tanh(c_new)

            // ---- gather current h: 1 DPP + 1 cvt_pkrtz + 7 indep DPP ----
            const float h1 = dpp_f<0x121>(hl);       // ror:1 neighbor
            pk[0] = __builtin_amdgcn_cvt_pkrtz(hl, h1);
            pk[1] = dpp_h<0x122>(pk[0]);
            pk[2] = dpp_h<0x124>(pk[0]);
            pk[3] = dpp_h<0x126>(pk[0]);
            pk[4] = dpp_h<0x128>(pk[0]);
            pk[5] = dpp_h<0x12A>(pk[0]);
            pk[6] = dpp_h<0x12C>(pk[0]);
            pk[7] = dpp_h<0x12E>(pk[0]);

            // ---- out-projection: lane-local dot on rotated pack (no DPP
            //      chain, no cross-lane) -- every lane computes the full sum
            float pa = blin, pb = 0.0f;
            pa = __builtin_amdgcn_fdot2(pk[0], wlr[0], pa, false);
            pb = __builtin_amdgcn_fdot2(pk[4], wlr[4], pb, false);
            pa = __builtin_amdgcn_fdot2(pk[1], wlr[1], pa, false);
            pb = __builtin_amdgcn_fdot2(pk[5], wlr[5], pb, false);
            pa = __builtin_amdgcn_fdot2(pk[2], wlr[2], pa, false);
            pb = __builtin_amdgcn_fdot2(pk[6], wlr[6], pb, false);
            pa = __builtin_amdgcn_fdot2(pk[3], wlr[3], pa, false);
            pb = __builtin_amdgcn_fdot2(pk[7], wlr[7], pb, false);
            ov[s] = pa + pb;
        }
        if (sub == 0) {
            o4[t0] = make_float4(ov[0], ov[1], ov[2], ov[3]);
        }
        xv = xnext;
    }
}

extern "C" void kernel_launch(void* const* d_in, const int* in_sizes, int n_in,
                              void* d_out, int out_size, void* d_ws, size_t ws_size,
                              hipStream_t stream) {
    const float* x     = (const float*)d_in[0];
    const float* W_ih  = (const float*)d_in[1];
    const float* W_hh  = (const float*)d_in[2];
    const float* b_ih  = (const float*)d_in[3];
    const float* b_hh  = (const float*)d_in[4];
    const float* W_lin = (const float*)d_in[5];
    const float* b_lin = (const float*)d_in[6];
    float* out = (float*)d_out;

    dim3 grid(B_TOT / 16);   // 256 blocks of 16 elements
    dim3 block(256);         // 4 waves/block, 4 elements/wave -> 1024 waves
    lstm_seq_kernel<<<grid, block, 0, stream>>>(x, W_ih, W_hh, b_ih, b_hh,
                                                W_lin, b_lin, out);
}